// Round 1
// baseline (237.887 us; speedup 1.0000x reference)
//
#include <hip/hip_runtime.h>
#include <math.h>

#define NQ 10
#define DIM 1024          // 2^NQ
#define NT 256            // threads per block
#define NLAYERS 4
#define APT (DIM / NT)    // amplitudes per thread = 4
#define PPT ((DIM/2)/NT)  // pairs per thread = 2

__device__ __forceinline__ float2 cmul(float2 a, float2 b) {
    return make_float2(a.x * b.x - a.y * b.y, a.x * b.y + a.y * b.x);
}

__global__ __launch_bounds__(NT) void qsim_kernel(const float* __restrict__ x,
                                                  const float* __restrict__ w,
                                                  float* __restrict__ out)
{
    __shared__ float2 st[DIM];
    __shared__ float red[NT / 64][NQ];

    const int t = threadIdx.x;
    const int sample = blockIdx.x;
    const float* xs = x + (long)sample * (2 * NQ);

    // init |0...0>
    #pragma unroll
    for (int k = 0; k < APT; ++k) st[t + k * NT] = make_float2(0.f, 0.f);
    if (t == 0) st[0] = make_float2(1.f, 0.f);
    __syncthreads();

    // ---------- encoding layer: fused U = RZ(phi) * RY(theta) * H ----------
    for (int q = 0; q < NQ; ++q) {
        float th = 0.7853981633974483f * (xs[q] + 1.0f);       // theta/2 = pi*(x+1)/4
        float ph = 0.7853981633974483f * (xs[NQ + q] + 1.0f);  // phi/2
        float cy, sy, cp, sp;
        sincosf(th, &sy, &cy);
        sincosf(ph, &sp, &cp);
        const float inv = 0.7071067811865476f;
        float a = (cy - sy) * inv;
        float b = (cy + sy) * inv;
        // u00 = e^{-i phi/2} * a ; u01 = e^{-i phi/2} * b
        // u10 = e^{+i phi/2} * b ; u11 = e^{+i phi/2} * (-a)
        float2 u00 = make_float2( cp * a, -sp * a);
        float2 u01 = make_float2( cp * b, -sp * b);
        float2 u10 = make_float2( cp * b,  sp * b);
        float2 u11 = make_float2(-cp * a, -sp * a);

        const int p = NQ - 1 - q, m = 1 << p;
        #pragma unroll
        for (int k = 0; k < PPT; ++k) {
            int j  = t + k * NT;
            int i0 = ((j >> p) << (p + 1)) | (j & (m - 1));
            int i1 = i0 | m;
            float2 s0 = st[i0], s1 = st[i1];
            float2 n0 = cmul(u00, s0), a1 = cmul(u01, s1);
            float2 n1 = cmul(u10, s0), a2 = cmul(u11, s1);
            n0.x += a1.x; n0.y += a1.y;
            n1.x += a2.x; n1.y += a2.y;
            st[i0] = n0; st[i1] = n1;
        }
        __syncthreads();
    }

    // ---------- variational layers ----------
    for (int l = 0; l < NLAYERS; ++l) {
        for (int q = 0; q < NQ; ++q) {
            const float* wq = w + (l * NQ + q) * 3;
            float w0 = wq[0], w1 = wq[1], w2 = wq[2];
            float hs = 0.5f * (w0 + w2);   // (w0+w2)/2
            float hd = 0.5f * (w0 - w2);   // (w0-w2)/2
            float hy = 0.5f * w1;
            float cy, sy, cs_, ss_, cd, sd;
            sincosf(hy, &sy, &cy);
            sincosf(hs, &ss_, &cs_);
            sincosf(hd, &sd, &cd);
            // U = RZ(w2) RY(w1) RZ(w0):
            // u00 = cy e^{-i hs}; u01 = -sy e^{+i hd}; u10 = sy e^{-i hd}; u11 = cy e^{+i hs}
            float2 u00 = make_float2( cy * cs_, -cy * ss_);
            float2 u01 = make_float2(-sy * cd,  -sy * sd);
            float2 u10 = make_float2( sy * cd,  -sy * sd);
            float2 u11 = make_float2( cy * cs_,  cy * ss_);

            const int p = NQ - 1 - q, m = 1 << p;
            #pragma unroll
            for (int k = 0; k < PPT; ++k) {
                int j  = t + k * NT;
                int i0 = ((j >> p) << (p + 1)) | (j & (m - 1));
                int i1 = i0 | m;
                float2 s0 = st[i0], s1 = st[i1];
                float2 n0 = cmul(u00, s0), a1 = cmul(u01, s1);
                float2 n1 = cmul(u10, s0), a2 = cmul(u11, s1);
                n0.x += a1.x; n0.y += a1.y;
                n1.x += a2.x; n1.y += a2.y;
                st[i0] = n0; st[i1] = n1;
            }
            __syncthreads();
        }

        // CNOT ring: for i in 0..9: CNOT(ctrl=i, tgt=(i+off)%10), applied sequentially.
        // Scatter: amplitude at idx ends up at c_9(...c_0(idx)...); each c_k flips
        // tgt bit iff ctrl bit (of the current index) is 1. Bit of qubit q = (9-q).
        const int off = (l & 1) ? (NQ / 2) : 1;
        float2 v[APT]; int dst[APT];
        #pragma unroll
        for (int k = 0; k < APT; ++k) {
            int idx = t + k * NT;
            v[k] = st[idx];
            int d = idx;
            #pragma unroll
            for (int i = 0; i < NQ; ++i) {
                int tt = i + off; if (tt >= NQ) tt -= NQ;
                int cb = (d >> (NQ - 1 - i)) & 1;
                d ^= cb << (NQ - 1 - tt);
            }
            dst[k] = d;
        }
        __syncthreads();
        #pragma unroll
        for (int k = 0; k < APT; ++k) st[dst[k]] = v[k];
        __syncthreads();
    }

    // ---------- measurement: <Z_q> = sum p * (1 - 2*bit_q) ----------
    float acc[NQ];
    #pragma unroll
    for (int q = 0; q < NQ; ++q) acc[q] = 0.f;
    #pragma unroll
    for (int k = 0; k < APT; ++k) {
        int idx = t + k * NT;
        float2 a = st[idx];
        float pr = a.x * a.x + a.y * a.y;
        #pragma unroll
        for (int q = 0; q < NQ; ++q)
            acc[q] += ((idx >> (NQ - 1 - q)) & 1) ? -pr : pr;
    }
    #pragma unroll
    for (int q = 0; q < NQ; ++q) {
        #pragma unroll
        for (int o = 32; o >= 1; o >>= 1)
            acc[q] += __shfl_xor(acc[q], o);
    }
    const int wave = t >> 6, lane = t & 63;
    if (lane == 0) {
        #pragma unroll
        for (int q = 0; q < NQ; ++q) red[wave][q] = acc[q];
    }
    __syncthreads();
    if (t < NQ) {
        float r = red[0][t] + red[1][t] + red[2][t] + red[3][t];
        out[(long)sample * NQ + t] = r;
    }
}

extern "C" void kernel_launch(void* const* d_in, const int* in_sizes, int n_in,
                              void* d_out, int out_size, void* d_ws, size_t ws_size,
                              hipStream_t stream) {
    const float* x = (const float*)d_in[0];   // (16,256,20) fp32
    const float* w = (const float*)d_in[1];   // (4,10,3)   fp32
    float* out = (float*)d_out;               // (16,256,10) fp32
    const int n_samples = in_sizes[0] / (2 * NQ);  // 4096
    qsim_kernel<<<n_samples, NT, 0, stream>>>(x, w, out);
}

// Round 2
// 119.306 us; speedup vs baseline: 1.9939x; 1.9939x over previous
//
#include <hip/hip_runtime.h>
#include <math.h>

#define NQ 10
#define DIM 1024          // 2^NQ
#define NT 256            // threads per block
#define NLAYERS 4
#define APT (DIM / NT)    // amplitudes per thread = 4

// ---- fused complex 2x2 apply: (s0,s1) <- U * (s0,s1) ----
__device__ __forceinline__ void apply2(float2 u00, float2 u01, float2 u10, float2 u11,
                                       float2& s0, float2& s1) {
    float2 n0, n1;
    n0.x = u00.x*s0.x - u00.y*s0.y + u01.x*s1.x - u01.y*s1.y;
    n0.y = u00.x*s0.y + u00.y*s0.x + u01.x*s1.y + u01.y*s1.x;
    n1.x = u10.x*s0.x - u10.y*s0.y + u11.x*s1.x - u11.y*s1.y;
    n1.y = u10.x*s0.y + u10.y*s0.x + u11.x*s1.y + u11.y*s1.x;
    s0 = n0; s1 = n1;
}

// ---- fused 2-qubit (adjacent bit) double gate: Ua on bit pb+1, Ub on bit pb ----
__device__ __forceinline__ void dgate(float2* st, int t, int pb,
        float2 a00, float2 a01, float2 a10, float2 a11,
        float2 b00, float2 b01, float2 b10, float2 b11) {
    int lo  = t & ((1 << pb) - 1);
    int i00 = ((t >> pb) << (pb + 2)) | lo;
    int i01 = i00 | (1 << pb);
    int i10 = i00 | (2 << pb);
    int i11 = i00 | (3 << pb);
    float2 s00 = st[i00], s01 = st[i01], s10 = st[i10], s11 = st[i11];
    apply2(b00, b01, b10, b11, s00, s01);
    apply2(b00, b01, b10, b11, s10, s11);
    apply2(a00, a01, a10, a11, s00, s10);
    apply2(a00, a01, a10, a11, s01, s11);
    st[i00] = s00; st[i01] = s01; st[i10] = s10; st[i11] = s11;
}

// ---- one-time: 40 variational gate matrices U = RZ(w2) RY(w1) RZ(w0) ----
__global__ void setup_mats(const float* __restrict__ w, float2* __restrict__ mats) {
    int g = threadIdx.x;
    if (g >= NLAYERS * NQ) return;
    float w0 = w[g*3+0], w1 = w[g*3+1], w2 = w[g*3+2];
    float hs = 0.5f*(w0 + w2), hd = 0.5f*(w0 - w2), hy = 0.5f*w1;
    float cy, sy, cs, ss, cd, sd;
    sincosf(hy, &sy, &cy);
    sincosf(hs, &ss, &cs);
    sincosf(hd, &sd, &cd);
    mats[g*4+0] = make_float2( cy*cs, -cy*ss);
    mats[g*4+1] = make_float2(-sy*cd, -sy*sd);
    mats[g*4+2] = make_float2( sy*cd, -sy*sd);
    mats[g*4+3] = make_float2( cy*cs,  cy*ss);
}

__global__ __launch_bounds__(NT) void qsim_kernel(const float* __restrict__ x,
                                                  const float2* __restrict__ mats,
                                                  float* __restrict__ out)
{
    __shared__ float2 st[DIM];
    __shared__ float2 enc[NQ][4];
    __shared__ float red[NT / 64][NQ];

    const int t = threadIdx.x;
    const float* xs = x + (long)blockIdx.x * (2 * NQ);

    // init |0...0>
    #pragma unroll
    for (int k = 0; k < APT; ++k) st[t + k * NT] = make_float2(0.f, 0.f);
    if (t == 0) st[0] = make_float2(1.f, 0.f);

    // encoding matrices: U = RZ(phi) RY(theta) H, one thread per qubit
    if (t < NQ) {
        float th = 0.7853981633974483f * (xs[t] + 1.0f);      // theta/2
        float ph = 0.7853981633974483f * (xs[NQ + t] + 1.0f); // phi/2
        float cy, sy, cp, sp;
        sincosf(th, &sy, &cy);
        sincosf(ph, &sp, &cp);
        const float inv = 0.7071067811865476f;
        float a = (cy - sy) * inv, b = (cy + sy) * inv;
        enc[t][0] = make_float2( cp * a, -sp * a);
        enc[t][1] = make_float2( cp * b, -sp * b);
        enc[t][2] = make_float2( cp * b,  sp * b);
        enc[t][3] = make_float2(-cp * a, -sp * a);
    }

    // CNOT scatter destinations (sequential ring; control bit of evolving index)
    int dst1[APT], dst5[APT];
    #pragma unroll
    for (int k = 0; k < APT; ++k) {
        int idx = t + k * NT;
        int d1 = idx, d5 = idx;
        #pragma unroll
        for (int i = 0; i < NQ; ++i) {
            int t1 = i + 1;      if (t1 >= NQ) t1 -= NQ;
            int t5 = i + NQ / 2; if (t5 >= NQ) t5 -= NQ;
            d1 ^= ((d1 >> (NQ - 1 - i)) & 1) << (NQ - 1 - t1);
            d5 ^= ((d5 >> (NQ - 1 - i)) & 1) << (NQ - 1 - t5);
        }
        dst1[k] = d1; dst5[k] = d5;
    }
    __syncthreads();

    // ---------- encoding: 5 double gates on qubit pairs (0,1)..(8,9) ----------
    #pragma unroll
    for (int j = 0; j < 5; ++j) {
        const int qa = 2 * j, qb = 2 * j + 1;
        const int pb = 8 - 2 * j;   // bit of qubit qb; qubit qa is bit pb+1
        dgate(st, t, pb,
              enc[qa][0], enc[qa][1], enc[qa][2], enc[qa][3],
              enc[qb][0], enc[qb][1], enc[qb][2], enc[qb][3]);
        __syncthreads();
    }

    // ---------- variational layers ----------
    #pragma unroll
    for (int l = 0; l < NLAYERS; ++l) {
        #pragma unroll
        for (int j = 0; j < 5; ++j) {
            const int qa = 2 * j, qb = 2 * j + 1;
            const int pb = 8 - 2 * j;
            const float2* ma = &mats[(l * NQ + qa) * 4];
            const float2* mb = &mats[(l * NQ + qb) * 4];
            dgate(st, t, pb,
                  ma[0], ma[1], ma[2], ma[3],
                  mb[0], mb[1], mb[2], mb[3]);
            __syncthreads();
        }
        // CNOT ring permutation (scatter)
        float2 v[APT];
        #pragma unroll
        for (int k = 0; k < APT; ++k) v[k] = st[t + k * NT];
        __syncthreads();
        #pragma unroll
        for (int k = 0; k < APT; ++k) {
            int d = (l & 1) ? dst5[k] : dst1[k];
            st[d] = v[k];
        }
        __syncthreads();
    }

    // ---------- measurement ----------
    float acc[NQ];
    #pragma unroll
    for (int q = 0; q < NQ; ++q) acc[q] = 0.f;
    #pragma unroll
    for (int k = 0; k < APT; ++k) {
        int idx = t + k * NT;
        float2 a = st[idx];
        float pr = a.x * a.x + a.y * a.y;
        #pragma unroll
        for (int q = 0; q < NQ; ++q)
            acc[q] += ((idx >> (NQ - 1 - q)) & 1) ? -pr : pr;
    }
    #pragma unroll
    for (int q = 0; q < NQ; ++q) {
        #pragma unroll
        for (int o = 32; o >= 1; o >>= 1)
            acc[q] += __shfl_xor(acc[q], o);
    }
    const int wave = t >> 6, lane = t & 63;
    if (lane == 0) {
        #pragma unroll
        for (int q = 0; q < NQ; ++q) red[wave][q] = acc[q];
    }
    __syncthreads();
    if (t < NQ) {
        out[(long)blockIdx.x * NQ + t] = red[0][t] + red[1][t] + red[2][t] + red[3][t];
    }
}

extern "C" void kernel_launch(void* const* d_in, const int* in_sizes, int n_in,
                              void* d_out, int out_size, void* d_ws, size_t ws_size,
                              hipStream_t stream) {
    const float* x = (const float*)d_in[0];   // (16,256,20) fp32
    const float* w = (const float*)d_in[1];   // (4,10,3)   fp32
    float* out = (float*)d_out;               // (16,256,10) fp32
    float2* mats = (float2*)d_ws;             // 40 gates x 4 complex entries
    const int n_samples = in_sizes[0] / (2 * NQ);  // 4096
    setup_mats<<<1, 64, 0, stream>>>(w, mats);
    qsim_kernel<<<n_samples, NT, 0, stream>>>(x, mats, out);
}